// Round 1
// baseline (2895.410 us; speedup 1.0000x reference)
//
#include <hip/hip_runtime.h>
#include <math.h>

#define B_ 32
#define L_ 256
#define C_ 55
#define D_ 512
#define H_ 8
#define NL_ 3
#define DF_ 512
#define Z_ 16
#define DK_ 64

// ---------------- block reduce (256 threads = 4 waves) ----------------
__device__ __forceinline__ float blockReduceSum(float v, float* sm) {
#pragma unroll
  for (int off = 32; off > 0; off >>= 1) v += __shfl_xor(v, off, 64);
  int wid = threadIdx.x >> 6;
  if ((threadIdx.x & 63) == 0) sm[wid] = v;
  __syncthreads();
  float r = sm[0] + sm[1] + sm[2] + sm[3];
  __syncthreads();
  return r;
}

// ---------------- generic tiled GEMM: C = act(alpha * A @ op(B) + bias) ----
// A: (M,K) row-major, lda.  BTRANS: B is (N,K) row-major (Y = X @ W^T).
// !BTRANS: B is (K,N) row-major.  Batched via blockIdx.z decomposed as
// (zb, zh) = (z / batchH, z % batchH), offset = zb*s1 + zh*s2 per matrix.
// ACT: 0 none, 1 exact gelu, 2 relu.
template <int ACT, bool BTRANS>
__global__ __launch_bounds__(256) void gemm_kernel(
    const float* __restrict__ A, const float* __restrict__ Bm,
    const float* __restrict__ bias, float* __restrict__ C,
    int M, int N, int K, int lda, int ldb, int ldc,
    int batchH, long sA1, long sA2, long sB1, long sB2, long sC1, long sC2,
    float alpha) {
  __shared__ float As[16][65];
  __shared__ float Bs[16][65];
  int t = threadIdx.x;
  int tx = t & 15, ty = t >> 4;
  int n0 = blockIdx.x * 64, m0 = blockIdx.y * 64;
  int zb = blockIdx.z / batchH, zh = blockIdx.z % batchH;
  const float* Ab = A + zb * sA1 + zh * sA2;
  const float* Bb = Bm + zb * sB1 + zh * sB2;
  float* Cb = C + zb * sC1 + zh * sC2;
  float acc[4][4] = {};
  for (int k0 = 0; k0 < K; k0 += 16) {
#pragma unroll
    for (int e = 0; e < 4; ++e) {
      int idx = t + e * 256;
      int mi = idx >> 4, ki = idx & 15;
      int m = m0 + mi, kk = k0 + ki;
      As[ki][mi] = (m < M && kk < K) ? Ab[(long)m * lda + kk] : 0.f;
      if (BTRANS) {
        int n = n0 + mi;
        Bs[ki][mi] = (n < N && kk < K) ? Bb[(long)n * ldb + kk] : 0.f;
      } else {
        int ni = idx & 63, ki2 = idx >> 6;
        int n = n0 + ni, kk2 = k0 + ki2;
        Bs[ki2][ni] = (n < N && kk2 < K) ? Bb[(long)kk2 * ldb + n] : 0.f;
      }
    }
    __syncthreads();
#pragma unroll
    for (int kk = 0; kk < 16; ++kk) {
      float a[4], b[4];
#pragma unroll
      for (int i = 0; i < 4; ++i) a[i] = As[kk][ty + 16 * i];
#pragma unroll
      for (int j = 0; j < 4; ++j) b[j] = Bs[kk][tx + 16 * j];
#pragma unroll
      for (int i = 0; i < 4; ++i)
#pragma unroll
        for (int j = 0; j < 4; ++j) acc[i][j] = fmaf(a[i], b[j], acc[i][j]);
    }
    __syncthreads();
  }
#pragma unroll
  for (int i = 0; i < 4; ++i) {
    int m = m0 + ty + 16 * i;
    if (m >= M) continue;
#pragma unroll
    for (int j = 0; j < 4; ++j) {
      int n = n0 + tx + 16 * j;
      if (n >= N) continue;
      float v = acc[i][j] * alpha;
      if (bias) v += bias[n];
      if (ACT == 1) v = 0.5f * v * (1.f + erff(v * 0.70710678118654752f));
      if (ACT == 2) v = fmaxf(v, 0.f);
      Cb[(long)m * ldc + n] = v;
    }
  }
}

// ---------------- row softmax over 256-length rows; 1 wave per row ---------
__global__ __launch_bounds__(256) void softmax_kernel(float* __restrict__ data) {
  long row = (long)blockIdx.x * 4 + (threadIdx.x >> 6);
  int lane = threadIdx.x & 63;
  float4* p = reinterpret_cast<float4*>(data + row * 256) + lane;
  float4 x = *p;
  float m = fmaxf(fmaxf(x.x, x.y), fmaxf(x.z, x.w));
#pragma unroll
  for (int off = 32; off > 0; off >>= 1) m = fmaxf(m, __shfl_xor(m, off, 64));
  x.x = expf(x.x - m);
  x.y = expf(x.y - m);
  x.z = expf(x.z - m);
  x.w = expf(x.w - m);
  float s = x.x + x.y + x.z + x.w;
#pragma unroll
  for (int off = 32; off > 0; off >>= 1) s += __shfl_xor(s, off, 64);
  float inv = 1.f / s;
  x.x *= inv;
  x.y *= inv;
  x.z *= inv;
  x.w *= inv;
  *p = x;
}

// ---------------- prior: fused sigma projection + Gaussian row -------------
// grid = B*H*L blocks (ordered as ((b*H+h)*L + l)), 256 threads (one per s).
__global__ __launch_bounds__(256) void prior_kernel(
    const float* __restrict__ hbuf, const float* __restrict__ sw,
    const float* __restrict__ sb, float* __restrict__ out) {
  __shared__ float sm[4];
  int bi = blockIdx.x;
  int l = bi & (L_ - 1);
  int bh = bi >> 8;         // / L_
  int hd = bh & (H_ - 1);
  int b = bh >> 3;          // / H_
  const float* hrow = hbuf + (long)(b * L_ + l) * D_;
  const float* wrow = sw + hd * D_;
  int t = threadIdx.x;
  float part = hrow[t] * wrow[t] + hrow[t + 256] * wrow[t + 256];
  float sig = blockReduceSum(part, sm) + sb[hd];
  sig = 1.f / (1.f + expf(-5.f * sig));      // sigmoid(5x)
  sig += 1e-5f;
  sig = expf(sig * 1.0986122886681098f) - 1.f;  // 3^sig - 1
  float coef = 0.3989422804014327f / sig;       // 1/(sqrt(2pi)*sig)
  float c2 = -0.5f / (sig * sig);
  float d = (float)(l - t);
  out[(long)bi * L_ + t] = coef * expf(c2 * d * d);
}

// ---------------- residual + layernorm: out = LN(a (+ r)) * g + b ----------
__global__ __launch_bounds__(256) void ln_kernel(
    const float* __restrict__ a, const float* __restrict__ r,
    const float* __restrict__ g, const float* __restrict__ be,
    float* __restrict__ out) {
  __shared__ float sm[4];
  long row = blockIdx.x;
  int t = threadIdx.x;
  const float* ar = a + row * D_;
  float x0 = ar[t], x1 = ar[t + 256];
  if (r) {
    const float* rr = r + row * D_;
    x0 += rr[t];
    x1 += rr[t + 256];
  }
  float mean = blockReduceSum(x0 + x1, sm) * (1.f / D_);
  float d0 = x0 - mean, d1 = x1 - mean;
  float var = blockReduceSum(d0 * d0 + d1 * d1, sm) * (1.f / D_);
  float rstd = rsqrtf(var + 1e-5f);
  float* orow = out + row * D_;
  orow[t] = d0 * rstd * g[t] + be[t];
  orow[t + 256] = d1 * rstd * g[t + 256] + be[t + 256];
}

// ---------------- embedding: circular conv1d(C->D, k=3) + sinusoidal PE ----
// grid = B * (L/16) blocks; each block does 16 sequence positions.
__global__ __launch_bounds__(256) void embed_kernel(
    const float* __restrict__ x, const float* __restrict__ tw,
    float* __restrict__ hout) {
  __shared__ float xs[18][56];
  int bi = blockIdx.x;
  int lt = (bi & 15) * 16;
  int b = bi >> 4;
  int t = threadIdx.x;
  for (int idx = t; idx < 18 * 55; idx += 256) {
    int rr = idx / 55, cc = idx % 55;
    int gl = (lt + rr - 1 + L_) & (L_ - 1);  // circular pad
    xs[rr][cc] = x[(long)(b * L_ + gl) * C_ + cc];
  }
  __syncthreads();
  for (int dp = 0; dp < 2; ++dp) {
    int d = t + dp * 256;
    float acc[16] = {};
    const float* wr = tw + (long)d * (C_ * 3);
    for (int c = 0; c < C_; ++c) {
#pragma unroll
      for (int w = 0; w < 3; ++w) {
        float wv = wr[c * 3 + w];
#pragma unroll
        for (int l = 0; l < 16; ++l) acc[l] = fmaf(xs[l + w][c], wv, acc[l]);
      }
    }
    // PE: even d -> sin(pos * exp(-d*ln(1e4)/512)), odd uses d-1, cos.
    float ang_scale = expf(-(float)(d & ~1) * 0.017988946039015984f);
#pragma unroll
    for (int l = 0; l < 16; ++l) {
      float ang = (float)(lt + l) * ang_scale;
      float pe = (d & 1) ? cosf(ang) : sinf(ang);
      hout[(long)(b * L_ + lt + l) * D_ + d] = acc[l] + pe;
    }
  }
}

extern "C" void kernel_launch(void* const* d_in, const int* in_sizes, int n_in,
                              void* d_out, int out_size, void* d_ws,
                              size_t ws_size, hipStream_t stream) {
  (void)in_sizes; (void)n_in; (void)out_size; (void)ws_size;
  const float* x = (const float*)d_in[0];
  const float* tok_w = (const float*)d_in[1];
  const float* qkv_w = (const float*)d_in[2];
  const float* qkv_b = (const float*)d_in[3];
  const float* sig_w = (const float*)d_in[4];
  const float* sig_b = (const float*)d_in[5];
  const float* out_w = (const float*)d_in[6];
  const float* out_b = (const float*)d_in[7];
  const float* c1w = (const float*)d_in[8];
  const float* c1b = (const float*)d_in[9];
  const float* c2w = (const float*)d_in[10];
  const float* c2b = (const float*)d_in[11];
  const float* ln1g = (const float*)d_in[12];
  const float* ln1b = (const float*)d_in[13];
  const float* ln2g = (const float*)d_in[14];
  const float* ln2b = (const float*)d_in[15];
  const float* lnfg = (const float*)d_in[16];
  const float* lnfb = (const float*)d_in[17];
  const float* latw = (const float*)d_in[18];
  const float* latb = (const float*)d_in[19];
  const float* d1w = (const float*)d_in[20];
  const float* d1b = (const float*)d_in[21];
  const float* d2w = (const float*)d_in[22];
  const float* d2b = (const float*)d_in[23];
  float* out = (float*)d_out;
  float* ws = (float*)d_ws;

  const long BLD = (long)B_ * L_ * D_;  // 4194304
  float* hb = ws;
  float* qb = ws + BLD;
  float* kb = ws + 2 * BLD;
  float* vb = ws + 3 * BLD;
  float* tb = ws + 4 * BLD;

  const long CHUNK = (long)B_ * H_ * L_ * L_;   // 16777216
  const long SER_OFF = (long)B_ * L_ * C_;      // 450560
  const long PRI_OFF = SER_OFF + NL_ * CHUNK;
  const long Z_OFF = PRI_OFF + NL_ * CHUNK;

  const int M = B_ * L_;  // 8192
  dim3 g8(8, M / 64, 1);

  embed_kernel<<<B_ * 16, 256, 0, stream>>>(x, tok_w, hb);

  for (int i = 0; i < NL_; ++i) {
    gemm_kernel<0, true><<<g8, 256, 0, stream>>>(
        hb, qkv_w + (long)(i * 3 + 0) * D_ * D_, qkv_b + (i * 3 + 0) * D_, qb,
        M, D_, D_, D_, D_, D_, 1, 0, 0, 0, 0, 0, 0, 1.f);
    gemm_kernel<0, true><<<g8, 256, 0, stream>>>(
        hb, qkv_w + (long)(i * 3 + 1) * D_ * D_, qkv_b + (i * 3 + 1) * D_, kb,
        M, D_, D_, D_, D_, D_, 1, 0, 0, 0, 0, 0, 0, 1.f);
    gemm_kernel<0, true><<<g8, 256, 0, stream>>>(
        hb, qkv_w + (long)(i * 3 + 2) * D_ * D_, qkv_b + (i * 3 + 2) * D_, vb,
        M, D_, D_, D_, D_, D_, 1, 0, 0, 0, 0, 0, 0, 1.f);
    prior_kernel<<<B_ * H_ * L_, 256, 0, stream>>>(
        hb, sig_w + (long)i * H_ * D_, sig_b + i * H_, out + PRI_OFF + i * CHUNK);
    float* ser = out + SER_OFF + i * CHUNK;
    // scores = (Q K^T) * 1/sqrt(DK), batched over (b,h)
    gemm_kernel<0, true><<<dim3(4, 4, B_ * H_), 256, 0, stream>>>(
        qb, kb, nullptr, ser, L_, L_, DK_, D_, D_, L_, H_, (long)L_ * D_, DK_,
        (long)L_ * D_, DK_, (long)H_ * L_ * L_, (long)L_ * L_, 0.125f);
    softmax_kernel<<<B_ * H_ * L_ / 4, 256, 0, stream>>>(ser);
    // PV: out(b,l,h,dk) = sum_s series * v   (NN GEMM), into qb
    gemm_kernel<0, false><<<dim3(1, 4, B_ * H_), 256, 0, stream>>>(
        ser, vb, nullptr, qb, L_, DK_, L_, L_, D_, D_, H_, (long)H_ * L_ * L_,
        (long)L_ * L_, (long)L_ * D_, DK_, (long)L_ * D_, DK_, 1.f);
    gemm_kernel<0, true><<<g8, 256, 0, stream>>>(
        qb, out_w + (long)i * D_ * D_, out_b + i * D_, tb, M, D_, D_, D_, D_,
        D_, 1, 0, 0, 0, 0, 0, 0, 1.f);
    ln_kernel<<<M, 256, 0, stream>>>(hb, tb, ln1g + i * D_, ln1b + i * D_, hb);
    gemm_kernel<1, true><<<g8, 256, 0, stream>>>(
        hb, c1w + (long)i * DF_ * D_, c1b + i * DF_, qb, M, DF_, D_, D_, D_,
        DF_, 1, 0, 0, 0, 0, 0, 0, 1.f);
    gemm_kernel<0, true><<<g8, 256, 0, stream>>>(
        qb, c2w + (long)i * D_ * DF_, c2b + i * D_, tb, M, D_, DF_, DF_, DF_,
        D_, 1, 0, 0, 0, 0, 0, 0, 1.f);
    ln_kernel<<<M, 256, 0, stream>>>(hb, tb, ln2g + i * D_, ln2b + i * D_, hb);
  }
  ln_kernel<<<M, 256, 0, stream>>>(hb, nullptr, lnfg, lnfb, qb);
  gemm_kernel<0, true><<<dim3(1, M / 64, 1), 256, 0, stream>>>(
      qb, latw, latb, out + Z_OFF, M, Z_, D_, D_, D_, Z_, 1, 0, 0, 0, 0, 0, 0,
      1.f);
  gemm_kernel<2, true><<<dim3(8, M / 64, 1), 256, 0, stream>>>(
      out + Z_OFF, d1w, d1b, tb, M, D_, Z_, Z_, Z_, D_, 1, 0, 0, 0, 0, 0, 0,
      1.f);
  gemm_kernel<0, true><<<dim3(1, M / 64, 1), 256, 0, stream>>>(
      tb, d2w, d2b, out, M, C_, D_, D_, D_, C_, 1, 0, 0, 0, 0, 0, 0, 1.f);
}

// Round 2
// 1281.773 us; speedup vs baseline: 2.2589x; 2.2589x over previous
//
#include <hip/hip_runtime.h>
#include <math.h>

#define B_ 32
#define L_ 256
#define C_ 55
#define D_ 512
#define H_ 8
#define NL_ 3
#define DF_ 512
#define Z_ 16
#define DK_ 64

typedef unsigned short u16;
typedef __attribute__((ext_vector_type(8))) short bf16x8;
typedef __attribute__((ext_vector_type(4))) float f32x4;

__device__ __forceinline__ float bf2f(u16 u) {
  unsigned v = ((unsigned)u) << 16;
  return __builtin_bit_cast(float, v);
}
__device__ __forceinline__ u16 f2bf(float f) {
  unsigned u = __builtin_bit_cast(unsigned, f);
  u += 0x7fffu + ((u >> 16) & 1u);
  return (u16)(u >> 16);
}
__device__ __forceinline__ void gload16(const void* g, void* l) {
  __builtin_amdgcn_global_load_lds(
      (const __attribute__((address_space(1))) unsigned*)g,
      (__attribute__((address_space(3))) unsigned*)l, 16, 0, 0);
}

// ---------------- block reduce (256 threads = 4 waves) ----------------
__device__ __forceinline__ float blockReduceSum(float v, float* sm) {
#pragma unroll
  for (int off = 32; off > 0; off >>= 1) v += __shfl_xor(v, off, 64);
  int wid = threadIdx.x >> 6;
  if ((threadIdx.x & 63) == 0) sm[wid] = v;
  __syncthreads();
  float r = sm[0] + sm[1] + sm[2] + sm[3];
  __syncthreads();
  return r;
}

// ================= MFMA GEMM: C = act(alpha * A @ B^T + bias) ==============
// A: (M,K) bf16 row-major; B: (N,K) bf16 row-major. SPLIT: hi/lo bf16x3.
// OUT: 0 fp32, 1 bf16, 2 bf16 split (hi+lo). ACT: 0 none, 1 exact gelu.
// Batched: z -> (zb=z/batchH, zh=z%batchH); offsets zb*s1 + zh*s2.
template <int WM, int WN, bool SPLIT, int ACT, int OUT>
__global__ __launch_bounds__(WM * WN * 64) void mgemm(
    const u16* __restrict__ Ah, const u16* __restrict__ Al,
    const u16* __restrict__ Bh, const u16* __restrict__ Bl,
    const float* __restrict__ bias, long sBb, float* __restrict__ Cf,
    u16* __restrict__ Ch, u16* __restrict__ Cl, int K, int lda, int ldb,
    int ldc, int batchH, long sA1, long sA2, long sB1, long sB2, long sC1,
    long sC2, float alpha) {
  constexpr int BM = WM * 64, BN = WN * 64, T = WM * WN * 64;
  __shared__ __align__(16) short As[BM * 32];
  __shared__ __align__(16) short Bs[BN * 32];
  __shared__ __align__(16) short Als[SPLIT ? BM * 32 : 8];
  __shared__ __align__(16) short Bls[SPLIT ? BN * 32 : 8];
  const int t = threadIdx.x, lane = t & 63, w = t >> 6;
  const int wm = w / WN, wn = w % WN;
  const int zb = blockIdx.z / batchH, zh = blockIdx.z % batchH;
  const long m0 = (long)blockIdx.y * BM, n0 = (long)blockIdx.x * BN;
  const char* Ab = (const char*)(Ah + zb * sA1 + zh * sA2 + m0 * lda);
  const char* Bb = (const char*)(Bh + zb * sB1 + zh * sB2 + n0 * ldb);
  const char* Alb =
      SPLIT ? (const char*)(Al + zb * sA1 + zh * sA2 + m0 * lda) : nullptr;
  const char* Blb =
      SPLIT ? (const char*)(Bl + zb * sB1 + zh * sB2 + n0 * ldb) : nullptr;
  const int fr = lane & 15, gq = lane >> 4;
  const int aoff = ((wm * 64 + fr) * 64 + gq * 16) >> 1;  // short index
  const int boff = ((wn * 64 + fr) * 64 + gq * 16) >> 1;
  const long lda2 = (long)lda * 2, ldb2 = (long)ldb * 2;
  f32x4 acc[4][4] = {};
  for (int k0 = 0; k0 < K; k0 += 32) {
    const long kb = (long)k0 * 2;
#pragma unroll
    for (int e = 0; e < BM * 4; e += T) {
      int d = (e + t) * 16;
      long src = (long)(d >> 6) * lda2 + kb + (d & 63);
      gload16(Ab + src, (char*)As + d);
      if (SPLIT) gload16(Alb + src, (char*)Als + d);
    }
#pragma unroll
    for (int e = 0; e < BN * 4; e += T) {
      int d = (e + t) * 16;
      long src = (long)(d >> 6) * ldb2 + kb + (d & 63);
      gload16(Bb + src, (char*)Bs + d);
      if (SPLIT) gload16(Blb + src, (char*)Bls + d);
    }
    __syncthreads();
    bf16x8 a[4], b[4], a2[4], b2[4];
#pragma unroll
    for (int m = 0; m < 4; ++m) {
      a[m] = *(const bf16x8*)(As + aoff + m * 512);
      if (SPLIT) a2[m] = *(const bf16x8*)(Als + aoff + m * 512);
    }
#pragma unroll
    for (int n = 0; n < 4; ++n) {
      b[n] = *(const bf16x8*)(Bs + boff + n * 512);
      if (SPLIT) b2[n] = *(const bf16x8*)(Bls + boff + n * 512);
    }
#pragma unroll
    for (int m = 0; m < 4; ++m)
#pragma unroll
      for (int n = 0; n < 4; ++n) {
        if (SPLIT) {
          acc[m][n] = __builtin_amdgcn_mfma_f32_16x16x32_bf16(a2[m], b[n],
                                                              acc[m][n], 0, 0, 0);
          acc[m][n] = __builtin_amdgcn_mfma_f32_16x16x32_bf16(a[m], b2[n],
                                                              acc[m][n], 0, 0, 0);
        }
        acc[m][n] =
            __builtin_amdgcn_mfma_f32_16x16x32_bf16(a[m], b[n], acc[m][n], 0, 0, 0);
      }
    __syncthreads();
  }
  float* Cfp = Cf ? Cf + zb * sC1 + zh * sC2 : nullptr;
  u16* Chp = Ch ? Ch + zb * sC1 + zh * sC2 : nullptr;
  u16* Clp = Cl ? Cl + zb * sC1 + zh * sC2 : nullptr;
  const float* bp = bias ? bias + zh * sBb : nullptr;
#pragma unroll
  for (int m = 0; m < 4; ++m) {
    long mg = m0 + wm * 64 + m * 16 + gq * 4;
#pragma unroll
    for (int n = 0; n < 4; ++n) {
      long ng = n0 + wn * 64 + n * 16 + fr;
      float bv = bp ? bp[ng] : 0.f;
#pragma unroll
      for (int r = 0; r < 4; ++r) {
        float v = acc[m][n][r] * alpha + bv;
        if (ACT == 1) v = 0.5f * v * (1.f + erff(v * 0.70710678118654752f));
        long idx = (mg + r) * ldc + ng;
        if (OUT == 0) Cfp[idx] = v;
        if (OUT >= 1) {
          u16 hv = f2bf(v);
          Chp[idx] = hv;
          if (OUT == 2) Clp[idx] = f2bf(v - bf2f(hv));
        }
      }
    }
  }
}

// ---------------- fp32 tiled GEMM (small decoder GEMMs only) ---------------
template <int ACT, bool BTRANS>
__global__ __launch_bounds__(256) void gemm_kernel(
    const float* __restrict__ A, const float* __restrict__ Bm,
    const float* __restrict__ bias, float* __restrict__ C, int M, int N, int K,
    int lda, int ldb, int ldc, float alpha) {
  __shared__ float Asm[16][65];
  __shared__ float Bsm[16][65];
  int t = threadIdx.x;
  int tx = t & 15, ty = t >> 4;
  int n0 = blockIdx.x * 64, m0 = blockIdx.y * 64;
  float acc[4][4] = {};
  for (int k0 = 0; k0 < K; k0 += 16) {
#pragma unroll
    for (int e = 0; e < 4; ++e) {
      int idx = t + e * 256;
      int mi = idx >> 4, ki = idx & 15;
      int m = m0 + mi, kk = k0 + ki;
      Asm[ki][mi] = (m < M && kk < K) ? A[(long)m * lda + kk] : 0.f;
      int n = n0 + mi;
      Bsm[ki][mi] = (n < N && kk < K) ? Bm[(long)n * ldb + kk] : 0.f;
    }
    __syncthreads();
#pragma unroll
    for (int kk = 0; kk < 16; ++kk) {
      float a[4], b[4];
#pragma unroll
      for (int i = 0; i < 4; ++i) a[i] = Asm[kk][ty + 16 * i];
#pragma unroll
      for (int j = 0; j < 4; ++j) b[j] = Bsm[kk][tx + 16 * j];
#pragma unroll
      for (int i = 0; i < 4; ++i)
#pragma unroll
        for (int j = 0; j < 4; ++j) acc[i][j] = fmaf(a[i], b[j], acc[i][j]);
    }
    __syncthreads();
  }
#pragma unroll
  for (int i = 0; i < 4; ++i) {
    int m = m0 + ty + 16 * i;
    if (m >= M) continue;
#pragma unroll
    for (int j = 0; j < 4; ++j) {
      int n = n0 + tx + 16 * j;
      if (n >= N) continue;
      float v = acc[i][j] * alpha;
      if (bias) v += bias[n];
      if (ACT == 2) v = fmaxf(v, 0.f);
      C[(long)m * ldc + n] = v;
    }
  }
}

// ---------------- convert fp32 -> bf16 (hi [+ lo]) -------------------------
__global__ __launch_bounds__(256) void convsplit(const float* __restrict__ in,
                                                 u16* __restrict__ oh,
                                                 u16* __restrict__ ol, int n) {
  int i = blockIdx.x * 256 + threadIdx.x;
  if (i >= n) return;
  float v = in[i];
  u16 h = f2bf(v);
  oh[i] = h;
  if (ol) ol[i] = f2bf(v - bf2f(h));
}

// ---------------- row softmax (256 cols), fp32 in place + bf16 copy --------
__global__ __launch_bounds__(256) void softmax_kernel(float* __restrict__ data,
                                                      u16* __restrict__ s16) {
  long row = (long)blockIdx.x * 4 + (threadIdx.x >> 6);
  int lane = threadIdx.x & 63;
  float4* p = reinterpret_cast<float4*>(data + row * 256) + lane;
  float4 x = *p;
  float m = fmaxf(fmaxf(x.x, x.y), fmaxf(x.z, x.w));
#pragma unroll
  for (int off = 32; off > 0; off >>= 1) m = fmaxf(m, __shfl_xor(m, off, 64));
  x.x = expf(x.x - m);
  x.y = expf(x.y - m);
  x.z = expf(x.z - m);
  x.w = expf(x.w - m);
  float s = x.x + x.y + x.z + x.w;
#pragma unroll
  for (int off = 32; off > 0; off >>= 1) s += __shfl_xor(s, off, 64);
  float inv = 1.f / s;
  x.x *= inv;
  x.y *= inv;
  x.z *= inv;
  x.w *= inv;
  *p = x;
  uint2 u;
  u.x = (unsigned)f2bf(x.x) | ((unsigned)f2bf(x.y) << 16);
  u.y = (unsigned)f2bf(x.z) | ((unsigned)f2bf(x.w) << 16);
  *reinterpret_cast<uint2*>(s16 + row * 256 + lane * 4) = u;
}

// ---------------- prior: fused sigma projection + Gaussian row -------------
__global__ __launch_bounds__(256) void prior_kernel(
    const float* __restrict__ hbuf, const float* __restrict__ sw,
    const float* __restrict__ sb, float* __restrict__ out) {
  __shared__ float sm[4];
  int bi = blockIdx.x;
  int l = bi & (L_ - 1);
  int bh = bi >> 8;
  int hd = bh & (H_ - 1);
  int b = bh >> 3;
  const float* hrow = hbuf + (long)(b * L_ + l) * D_;
  const float* wrow = sw + hd * D_;
  int t = threadIdx.x;
  float part = hrow[t] * wrow[t] + hrow[t + 256] * wrow[t + 256];
  float sig = blockReduceSum(part, sm) + sb[hd];
  sig = 1.f / (1.f + expf(-5.f * sig));
  sig += 1e-5f;
  sig = expf(sig * 1.0986122886681098f) - 1.f;
  float coef = 0.3989422804014327f / sig;
  float c2 = -0.5f / (sig * sig);
  float d = (float)(l - t);
  out[(long)bi * L_ + t] = coef * expf(c2 * d * d);
}

// ---------------- residual + layernorm (+ optional bf16 hi/lo mirror) ------
__global__ __launch_bounds__(256) void ln_kernel(
    const float* __restrict__ a, const float* __restrict__ r,
    const float* __restrict__ gg, const float* __restrict__ be,
    float* __restrict__ out, u16* __restrict__ oh, u16* __restrict__ ol) {
  __shared__ float sm[4];
  long row = blockIdx.x;
  int t = threadIdx.x;
  const float* ar = a + row * D_;
  float x0 = ar[t], x1 = ar[t + 256];
  if (r) {
    const float* rr = r + row * D_;
    x0 += rr[t];
    x1 += rr[t + 256];
  }
  float mean = blockReduceSum(x0 + x1, sm) * (1.f / D_);
  float d0 = x0 - mean, d1 = x1 - mean;
  float var = blockReduceSum(d0 * d0 + d1 * d1, sm) * (1.f / D_);
  float rstd = rsqrtf(var + 1e-5f);
  float v0 = d0 * rstd * gg[t] + be[t];
  float v1 = d1 * rstd * gg[t + 256] + be[t + 256];
  float* orow = out + row * D_;
  orow[t] = v0;
  orow[t + 256] = v1;
  if (oh) {
    u16 h0 = f2bf(v0), h1 = f2bf(v1);
    oh[row * D_ + t] = h0;
    oh[row * D_ + t + 256] = h1;
    if (ol) {
      ol[row * D_ + t] = f2bf(v0 - bf2f(h0));
      ol[row * D_ + t + 256] = f2bf(v1 - bf2f(h1));
    }
  }
}

// ---------------- embedding: circular conv1d + PE, fp32 + bf16 hi/lo -------
__global__ __launch_bounds__(256) void embed_kernel(
    const float* __restrict__ x, const float* __restrict__ tw,
    float* __restrict__ hout, u16* __restrict__ oh, u16* __restrict__ ol) {
  __shared__ float xs[18][56];
  int bi = blockIdx.x;
  int lt = (bi & 15) * 16;
  int b = bi >> 4;
  int t = threadIdx.x;
  for (int idx = t; idx < 18 * 55; idx += 256) {
    int rr = idx / 55, cc = idx % 55;
    int gl = (lt + rr - 1 + L_) & (L_ - 1);
    xs[rr][cc] = x[(long)(b * L_ + gl) * C_ + cc];
  }
  __syncthreads();
  for (int dp = 0; dp < 2; ++dp) {
    int d = t + dp * 256;
    float acc[16] = {};
    const float* wr = tw + (long)d * (C_ * 3);
    for (int c = 0; c < C_; ++c) {
#pragma unroll
      for (int w = 0; w < 3; ++w) {
        float wv = wr[c * 3 + w];
#pragma unroll
        for (int l = 0; l < 16; ++l) acc[l] = fmaf(xs[l + w][c], wv, acc[l]);
      }
    }
    float ang_scale = expf(-(float)(d & ~1) * 0.017988946039015984f);
#pragma unroll
    for (int l = 0; l < 16; ++l) {
      float ang = (float)(lt + l) * ang_scale;
      float pe = (d & 1) ? cosf(ang) : sinf(ang);
      float v = acc[l] + pe;
      long idx = (long)(b * L_ + lt + l) * D_ + d;
      hout[idx] = v;
      u16 h = f2bf(v);
      oh[idx] = h;
      ol[idx] = f2bf(v - bf2f(h));
    }
  }
}

extern "C" void kernel_launch(void* const* d_in, const int* in_sizes, int n_in,
                              void* d_out, int out_size, void* d_ws,
                              size_t ws_size, hipStream_t stream) {
  (void)in_sizes; (void)n_in; (void)out_size; (void)ws_size;
  const float* x = (const float*)d_in[0];
  const float* tok_w = (const float*)d_in[1];
  const float* qkv_w = (const float*)d_in[2];
  const float* qkv_b = (const float*)d_in[3];
  const float* sig_w = (const float*)d_in[4];
  const float* sig_b = (const float*)d_in[5];
  const float* out_w = (const float*)d_in[6];
  const float* out_b = (const float*)d_in[7];
  const float* c1w = (const float*)d_in[8];
  const float* c1b = (const float*)d_in[9];
  const float* c2w = (const float*)d_in[10];
  const float* c2b = (const float*)d_in[11];
  const float* ln1g = (const float*)d_in[12];
  const float* ln1b = (const float*)d_in[13];
  const float* ln2g = (const float*)d_in[14];
  const float* ln2b = (const float*)d_in[15];
  const float* lnfg = (const float*)d_in[16];
  const float* lnfb = (const float*)d_in[17];
  const float* latw = (const float*)d_in[18];
  const float* latb = (const float*)d_in[19];
  const float* d1w = (const float*)d_in[20];
  const float* d1b = (const float*)d_in[21];
  const float* d2w = (const float*)d_in[22];
  const float* d2b = (const float*)d_in[23];
  float* out = (float*)d_out;

  const long BLD = (long)B_ * L_ * D_;         // 4194304
  const long CHUNK = (long)B_ * H_ * L_ * L_;  // 16777216
  const long SER_OFF = (long)B_ * L_ * C_;
  const long PRI_OFF = SER_OFF + NL_ * CHUNK;
  const long Z_OFF = PRI_OFF + NL_ * CHUNK;
  const int M = B_ * L_;  // 8192
  const int DD = D_ * D_;

  char* wp = (char*)d_ws;
  auto alloc = [&](size_t bytes) {
    char* p = wp;
    wp += (bytes + 255) & ~(size_t)255;
    return p;
  };
  float* hb = (float*)alloc(BLD * 4);
  float* tb = (float*)alloc(BLD * 4);
  u16* hh = (u16*)alloc(BLD * 2);
  u16* hl = (u16*)alloc(BLD * 2);
  u16* qh = (u16*)alloc(BLD * 2);
  u16* ql = (u16*)alloc(BLD * 2);
  u16* kh = (u16*)alloc(BLD * 2);
  u16* kl = (u16*)alloc(BLD * 2);
  u16* vt = (u16*)alloc(BLD * 2);
  u16* pv = (u16*)alloc(BLD * 2);
  u16* sb16 = (u16*)alloc(CHUNK * 2);
  u16* wqkvh = (u16*)alloc((size_t)NL_ * 3 * DD * 2);
  u16* wqkvl = (u16*)alloc((size_t)NL_ * 3 * DD * 2);
  u16* woh = (u16*)alloc((size_t)NL_ * DD * 2);
  u16* c1h = (u16*)alloc((size_t)NL_ * DD * 2);
  u16* c2h = (u16*)alloc((size_t)NL_ * DD * 2);

  // weight conversion
  int nqkv = NL_ * 3 * DD;
  convsplit<<<(nqkv + 255) / 256, 256, 0, stream>>>(qkv_w, wqkvh, wqkvl, nqkv);
  convsplit<<<(NL_ * DD + 255) / 256, 256, 0, stream>>>(out_w, woh, nullptr, NL_ * DD);
  convsplit<<<(NL_ * DD + 255) / 256, 256, 0, stream>>>(c1w, c1h, nullptr, NL_ * DD);
  convsplit<<<(NL_ * DD + 255) / 256, 256, 0, stream>>>(c2w, c2h, nullptr, NL_ * DD);

  embed_kernel<<<B_ * 16, 256, 0, stream>>>(x, tok_w, hb, hh, hl);

  for (int i = 0; i < NL_; ++i) {
    const long ofQ = (long)(i * 3 + 0) * DD, ofK = (long)(i * 3 + 1) * DD,
               ofV = (long)(i * 3 + 2) * DD;
    // q, k projections: split-in, split-out
    mgemm<2, 2, true, 0, 2><<<dim3(4, 64, 1), 256, 0, stream>>>(
        hh, hl, wqkvh + ofQ, wqkvl + ofQ, qkv_b + (i * 3 + 0) * D_, 0, nullptr,
        qh, ql, D_, D_, D_, D_, 1, 0, 0, 0, 0, 0, 0, 1.f);
    mgemm<2, 2, true, 0, 2><<<dim3(4, 64, 1), 256, 0, stream>>>(
        hh, hl, wqkvh + ofK, wqkvl + ofK, qkv_b + (i * 3 + 1) * D_, 0, nullptr,
        kh, kl, D_, D_, D_, D_, 1, 0, 0, 0, 0, 0, 0, 1.f);
    // v transposed: vt(d, b*L+l) = Wv @ h^T   (bias folded into PV epilogue)
    mgemm<2, 2, false, 0, 1><<<dim3(64, 4, 1), 256, 0, stream>>>(
        wqkvh + ofV, nullptr, hh, nullptr, nullptr, 0, nullptr, vt, nullptr,
        D_, D_, D_, M, 1, 0, 0, 0, 0, 0, 0, 1.f);
    prior_kernel<<<B_ * H_ * L_, 256, 0, stream>>>(
        hb, sig_w + (long)i * H_ * D_, sig_b + i * H_, out + PRI_OFF + i * CHUNK);
    float* ser = out + SER_OFF + i * CHUNK;
    // scores = (Q K^T) / 8, split bf16x3, batched over (b,h)
    mgemm<2, 2, true, 0, 0><<<dim3(2, 2, B_ * H_), 256, 0, stream>>>(
        qh, ql, kh, kl, nullptr, 0, ser, nullptr, nullptr, DK_, D_, D_, L_, H_,
        (long)L_ * D_, 64, (long)L_ * D_, 64, (long)H_ * L_ * L_, (long)L_ * L_,
        0.125f);
    softmax_kernel<<<B_ * H_ * L_ / 4, 256, 0, stream>>>(ser, sb16);
    // PV: (b,h): series(L,L) @ vt(h-dk rows, b-l cols)^T + v-bias
    mgemm<2, 1, false, 0, 1><<<dim3(1, 2, B_ * H_), 128, 0, stream>>>(
        sb16, nullptr, vt, nullptr, qkv_b + (i * 3 + 2) * D_, 64, nullptr, pv,
        nullptr, L_, L_, M, D_, H_, (long)H_ * L_ * L_, (long)L_ * L_, 256,
        (long)64 * M, (long)L_ * D_, 64, 1.f);
    // out projection (fp32 out)
    mgemm<2, 2, false, 0, 0><<<dim3(4, 64, 1), 256, 0, stream>>>(
        pv, nullptr, woh + (long)i * DD, nullptr, out_b + i * D_, 0, tb,
        nullptr, nullptr, D_, D_, D_, D_, 1, 0, 0, 0, 0, 0, 0, 1.f);
    ln_kernel<<<M, 256, 0, stream>>>(hb, tb, ln1g + i * D_, ln1b + i * D_, hb,
                                     hh, hl);
    // FFN
    mgemm<2, 2, false, 1, 1><<<dim3(4, 64, 1), 256, 0, stream>>>(
        hh, nullptr, c1h + (long)i * DD, nullptr, c1b + i * DF_, 0, nullptr,
        qh, nullptr, D_, D_, D_, DF_, 1, 0, 0, 0, 0, 0, 0, 1.f);
    mgemm<2, 2, false, 0, 0><<<dim3(4, 64, 1), 256, 0, stream>>>(
        qh, nullptr, c2h + (long)i * DD, nullptr, c2b + i * D_, 0, tb, nullptr,
        nullptr, DF_, DF_, DF_, D_, 1, 0, 0, 0, 0, 0, 0, 1.f);
    ln_kernel<<<M, 256, 0, stream>>>(hb, tb, ln2g + i * D_, ln2b + i * D_, hb,
                                     hh, hl);
  }
  ln_kernel<<<M, 256, 0, stream>>>(hb, nullptr, lnfg, lnfb, tb, nullptr,
                                   nullptr);
  gemm_kernel<0, true><<<dim3(1, M / 64, 1), 256, 0, stream>>>(
      tb, latw, latb, out + Z_OFF, M, Z_, D_, D_, D_, Z_, 1.f);
  gemm_kernel<2, true><<<dim3(8, M / 64, 1), 256, 0, stream>>>(
      out + Z_OFF, d1w, d1b, hb, M, D_, Z_, Z_, Z_, D_, 1.f);
  gemm_kernel<0, true><<<dim3(1, M / 64, 1), 256, 0, stream>>>(
      hb, d2w, d2b, out, M, C_, D_, D_, D_, C_, 1.f);
}